// Round 6
// baseline (42.142 us; speedup 1.0000x reference)
//
#include <hip/hip_runtime.h>
#include <hip/hip_bf16.h>

#define LOG2E_F 1.4426950408889634f

typedef __attribute__((ext_vector_type(8))) short short8;
typedef __attribute__((ext_vector_type(4))) float f32x4;

__device__ inline unsigned short f2b(float f) {
    __hip_bfloat16 h = __float2bfloat16(f);   // RNE
    return *reinterpret_cast<unsigned short*>(&h);
}

// load 8 consecutive fp32 and convert to one bf16 MFMA fragment (short8)
__device__ inline short8 load_frag_f32(const float* p) {
    const float4 lo = *(const float4*)p;
    const float4 hi = *(const float4*)(p + 4);
    short8 r;
    r[0] = (short)f2b(lo.x); r[1] = (short)f2b(lo.y);
    r[2] = (short)f2b(lo.z); r[3] = (short)f2b(lo.w);
    r[4] = (short)f2b(hi.x); r[5] = (short)f2b(hi.y);
    r[6] = (short)f2b(hi.z); r[7] = (short)f2b(hi.w);
    return r;
}

// =====================================================================
// Fully fused Crystalformer layer, 8-wave blocks for TLP.
// 512 blocks x 512 threads (8 waves); 2 blocks/CU -> 4 waves/SIMD
// (round 5 had 2 waves/SIMD, VALUBusy 30%: latency-bound at the
// quarter-rate v_exp_f32 issue floor ~12us/SIMD).
//   Phase 1: QKV bf16-MFMA -> LDS qkvl[3][32][164] fp32 (3 col-tiles/wave)
//   Phase 2: online-softmax lattice attention, kj-loop SPLIT across two
//            256-thread halves (16 kj each), merged once via LDS.
//   Phase 3: out-projection bf16-MFMA (1 col-tile/wave) -> d_out
// __launch_bounds__(512,4): 4 waves/EU -> VGPR cap 128 (2 blocks/CU).
// =====================================================================
__global__ __launch_bounds__(512, 4) void fused_attn_kernel(
    const float* __restrict__ x, const float* __restrict__ Win,
    const float* __restrict__ bin, const float* __restrict__ Wout,
    const float* __restrict__ bout, const float* __restrict__ alpha,
    const float* __restrict__ dist2, float* __restrict__ out)
{
    __shared__ float qkvl[3][32][164];          // 63.0 KB
    __shared__ unsigned short aggb[32][136];    //  8.7 KB

    const int sys  = blockIdx.x;
    const int tid  = threadIdx.x;               // 0..511
    const int lane = tid & 63;
    const int wv   = tid >> 6;                  // 0..7
    const int r16  = lane & 15;
    const int kg   = lane >> 4;
    const int base = sys << 5;

    // ---------------- Phase 1: QKV projection into LDS ----------------
    short8 af[2][4];
    #pragma unroll
    for (int rt = 0; rt < 2; ++rt)
        #pragma unroll
        for (int ks = 0; ks < 4; ++ks)
            af[rt][ks] = load_frag_f32(
                x + (size_t)(base + rt * 16 + r16) * 128 + ks * 32 + kg * 8);

    // wave wv owns col-tiles [3wv, 3wv+3) of 24 (384 cols).
    #pragma unroll
    for (int j = 0; j < 3; ++j) {
        const int ct = wv * 3 + j;            // 0..23 (wave-uniform)
        const int c  = ct * 16 + r16;         // global col 0..383
        short8 bf[4];
        #pragma unroll
        for (int ks = 0; ks < 4; ++ks)
            bf[ks] = load_frag_f32(Win + (size_t)c * 128 + ks * 32 + kg * 8);
        const float bias_v = bin[c];
        const int   bufi   = ct >> 3;         // 0=q, 1=k, 2=v
        const int   hh     = ct & 7;
        const float scale  = (bufi == 0) ? 0.25f : 1.0f;   // q / sqrt(dh)

        #pragma unroll
        for (int rt = 0; rt < 2; ++rt) {
            f32x4 acc = {0.f, 0.f, 0.f, 0.f};
            #pragma unroll
            for (int ks = 0; ks < 4; ++ks)
                acc = __builtin_amdgcn_mfma_f32_16x16x32_bf16(af[rt][ks], bf[ks], acc, 0, 0, 0);
            // C/D: col = lane&15 (=r16 -> feature), row = kg*4+r (-> atom)
            #pragma unroll
            for (int r = 0; r < 4; ++r) {
                const int atom = rt * 16 + kg * 4 + r;
                qkvl[bufi][atom][hh * 20 + r16] = (acc[r] + bias_v) * scale;
            }
        }
    }

    const int t     = tid & 255;
    const int khalf = tid >> 8;                 // 0 or 1: which 16-kj half
    const int qi    = t >> 3;
    const int h     = t & 7;
    const float al2 = alpha[(size_t)(base + qi) * 8 + h] * LOG2E_F;   // < 0

    __syncthreads();

    // ---------------- Phase 2: online-softmax lattice attention --------
    float qreg[16];
    {
        const float* qrow = &qkvl[0][qi][h * 20];
        #pragma unroll
        for (int d4 = 0; d4 < 4; ++d4) {
            const float4 tq = *(const float4*)(qrow + (d4 << 2));
            qreg[d4 * 4 + 0] = tq.x; qreg[d4 * 4 + 1] = tq.y;
            qreg[d4 * 4 + 2] = tq.z; qreg[d4 * 4 + 3] = tq.w;
        }
    }

    float m = -1e30f;
    float den = 0.f;
    float acc[16] = {};
    const float* dp = dist2 + ((size_t)(sys * 1024 + qi * 32) + khalf * 16) * 16;

    #pragma unroll
    for (int kk = 0; kk < 16; ++kk, dp += 16) {
        const int kj = khalf * 16 + kk;
        // lattice term: ssum = sum_r exp2(al2*(d2 - mn)), c0 = al2*mn
        const float4 t0 = *(const float4*)(dp + 0);
        const float4 t1 = *(const float4*)(dp + 4);
        const float4 t2 = *(const float4*)(dp + 8);
        const float4 t3 = *(const float4*)(dp + 12);
        const float mn = fminf(
            fminf(fminf(fminf(t0.x, t0.y), fminf(t0.z, t0.w)),
                  fminf(fminf(t1.x, t1.y), fminf(t1.z, t1.w))),
            fminf(fminf(fminf(t2.x, t2.y), fminf(t2.z, t2.w)),
                  fminf(fminf(t3.x, t3.y), fminf(t3.z, t3.w))));
        const float c0 = al2 * mn;   // = max_r(al2*d2), al2 < 0
        float e0 = __builtin_amdgcn_exp2f(fmaf(al2, t0.x, -c0));
        e0 += __builtin_amdgcn_exp2f(fmaf(al2, t0.y, -c0));
        e0 += __builtin_amdgcn_exp2f(fmaf(al2, t0.z, -c0));
        e0 += __builtin_amdgcn_exp2f(fmaf(al2, t0.w, -c0));
        float e1 = __builtin_amdgcn_exp2f(fmaf(al2, t1.x, -c0));
        e1 += __builtin_amdgcn_exp2f(fmaf(al2, t1.y, -c0));
        e1 += __builtin_amdgcn_exp2f(fmaf(al2, t1.z, -c0));
        e1 += __builtin_amdgcn_exp2f(fmaf(al2, t1.w, -c0));
        float e2 = __builtin_amdgcn_exp2f(fmaf(al2, t2.x, -c0));
        e2 += __builtin_amdgcn_exp2f(fmaf(al2, t2.y, -c0));
        e2 += __builtin_amdgcn_exp2f(fmaf(al2, t2.z, -c0));
        e2 += __builtin_amdgcn_exp2f(fmaf(al2, t2.w, -c0));
        float e3 = __builtin_amdgcn_exp2f(fmaf(al2, t3.x, -c0));
        e3 += __builtin_amdgcn_exp2f(fmaf(al2, t3.y, -c0));
        e3 += __builtin_amdgcn_exp2f(fmaf(al2, t3.z, -c0));
        e3 += __builtin_amdgcn_exp2f(fmaf(al2, t3.w, -c0));
        const float ssum = (e0 + e1) + (e2 + e3);   // in [1, 16]

        // q.k dot from LDS (wave-uniform row kj -> broadcast, conflict-free)
        const float* kr = &qkvl[1][kj][h * 20];
        const float4 k0 = *(const float4*)(kr + 0);
        const float4 k1 = *(const float4*)(kr + 4);
        const float4 k2 = *(const float4*)(kr + 8);
        const float4 k3 = *(const float4*)(kr + 12);
        float p0 = qreg[0] * k0.x, p1 = qreg[1] * k0.y;
        float p2 = qreg[2] * k0.z, p3 = qreg[3] * k0.w;
        p0 = fmaf(qreg[4],  k1.x, p0); p1 = fmaf(qreg[5],  k1.y, p1);
        p2 = fmaf(qreg[6],  k1.z, p2); p3 = fmaf(qreg[7],  k1.w, p3);
        p0 = fmaf(qreg[8],  k2.x, p0); p1 = fmaf(qreg[9],  k2.y, p1);
        p2 = fmaf(qreg[10], k2.z, p2); p3 = fmaf(qreg[11], k2.w, p3);
        p0 = fmaf(qreg[12], k3.x, p0); p1 = fmaf(qreg[13], k3.y, p1);
        p2 = fmaf(qreg[14], k3.z, p2); p3 = fmaf(qreg[15], k3.w, p3);
        const float dot = (p0 + p1) + (p2 + p3);

        const float b = fmaf(dot, LOG2E_F, c0);   // log2-domain score

        // deferred-max online rescale (THR = 8 in log2 domain)
        if (b - m > 8.0f) {
            const float sc = __builtin_amdgcn_exp2f(m - b);  // 0 on first hit
            den *= sc;
            #pragma unroll
            for (int d = 0; d < 16; ++d) acc[d] *= sc;
            m = b;
        }
        const float p = __builtin_amdgcn_exp2f(b - m) * ssum;  // <= 2^8 * 16
        den += p;

        // PV accumulate
        const float* vr = &qkvl[2][kj][h * 20];
        const float4 v0 = *(const float4*)(vr + 0);
        const float4 v1 = *(const float4*)(vr + 4);
        const float4 v2 = *(const float4*)(vr + 8);
        const float4 v3 = *(const float4*)(vr + 12);
        acc[0]  = fmaf(p, v0.x, acc[0]);  acc[1]  = fmaf(p, v0.y, acc[1]);
        acc[2]  = fmaf(p, v0.z, acc[2]);  acc[3]  = fmaf(p, v0.w, acc[3]);
        acc[4]  = fmaf(p, v1.x, acc[4]);  acc[5]  = fmaf(p, v1.y, acc[5]);
        acc[6]  = fmaf(p, v1.z, acc[6]);  acc[7]  = fmaf(p, v1.w, acc[7]);
        acc[8]  = fmaf(p, v2.x, acc[8]);  acc[9]  = fmaf(p, v2.y, acc[9]);
        acc[10] = fmaf(p, v2.z, acc[10]); acc[11] = fmaf(p, v2.w, acc[11]);
        acc[12] = fmaf(p, v3.x, acc[12]); acc[13] = fmaf(p, v3.y, acc[13]);
        acc[14] = fmaf(p, v3.z, acc[14]); acc[15] = fmaf(p, v3.w, acc[15]);
    }

    // ---- merge the two kj-halves (exchange through dead q-LDS region) ----
    __syncthreads();                       // q reads complete; q region reusable
    float* exch = &qkvl[0][0][0];          // 256 x 19 floats (stride 19: odd
                                           // -> consecutive lanes hit distinct banks)
    if (khalf == 1) {
        float* e = exch + t * 19;
        e[0] = m; e[1] = den;
        #pragma unroll
        for (int d = 0; d < 16; ++d) e[2 + d] = acc[d];
    }
    __syncthreads();
    if (khalf == 0) {
        const float* e = exch + t * 19;
        const float m2   = e[0];
        const float den2 = e[1];
        const float M  = fmaxf(m, m2);
        const float s1 = __builtin_amdgcn_exp2f(m - M);
        const float s2 = __builtin_amdgcn_exp2f(m2 - M);
        const float inv = 1.0f / (den * s1 + den2 * s2);
        const float a1 = s1 * inv, a2 = s2 * inv;

        unsigned short* op = &aggb[qi][h * 16];
        uint4 o0, o1;
        o0.x = (unsigned)f2b(fmaf(acc[0],  a1, e[2]  * a2)) | ((unsigned)f2b(fmaf(acc[1],  a1, e[3]  * a2)) << 16);
        o0.y = (unsigned)f2b(fmaf(acc[2],  a1, e[4]  * a2)) | ((unsigned)f2b(fmaf(acc[3],  a1, e[5]  * a2)) << 16);
        o0.z = (unsigned)f2b(fmaf(acc[4],  a1, e[6]  * a2)) | ((unsigned)f2b(fmaf(acc[5],  a1, e[7]  * a2)) << 16);
        o0.w = (unsigned)f2b(fmaf(acc[6],  a1, e[8]  * a2)) | ((unsigned)f2b(fmaf(acc[7],  a1, e[9]  * a2)) << 16);
        o1.x = (unsigned)f2b(fmaf(acc[8],  a1, e[10] * a2)) | ((unsigned)f2b(fmaf(acc[9],  a1, e[11] * a2)) << 16);
        o1.y = (unsigned)f2b(fmaf(acc[10], a1, e[12] * a2)) | ((unsigned)f2b(fmaf(acc[11], a1, e[13] * a2)) << 16);
        o1.z = (unsigned)f2b(fmaf(acc[12], a1, e[14] * a2)) | ((unsigned)f2b(fmaf(acc[13], a1, e[15] * a2)) << 16);
        o1.w = (unsigned)f2b(fmaf(acc[14], a1, e[16] * a2)) | ((unsigned)f2b(fmaf(acc[15], a1, e[17] * a2)) << 16);
        *(uint4*)op       = o0;
        *(uint4*)(op + 8) = o1;
    }

    __syncthreads();

    // ---------------- Phase 3: out-projection -------------------------
    // wave wv owns col-tile ct = wv (8 tiles = 128 cols), both row-tiles.
    short8 aA[2][4];
    #pragma unroll
    for (int rt = 0; rt < 2; ++rt)
        #pragma unroll
        for (int ks = 0; ks < 4; ++ks)
            aA[rt][ks] = *(const short8*)(&aggb[rt * 16 + r16][ks * 32 + kg * 8]);

    {
        const int c = wv * 16 + r16;          // 0..127
        short8 bf[4];
        #pragma unroll
        for (int ks = 0; ks < 4; ++ks)
            bf[ks] = load_frag_f32(Wout + (size_t)c * 128 + ks * 32 + kg * 8);
        const float bias_v = bout[c];
        #pragma unroll
        for (int rt = 0; rt < 2; ++rt) {
            f32x4 oacc = {0.f, 0.f, 0.f, 0.f};
            #pragma unroll
            for (int ks = 0; ks < 4; ++ks)
                oacc = __builtin_amdgcn_mfma_f32_16x16x32_bf16(aA[rt][ks], bf[ks], oacc, 0, 0, 0);
            #pragma unroll
            for (int r = 0; r < 4; ++r) {
                const int row = base + rt * 16 + kg * 4 + r;
                out[(size_t)row * 128 + c] = oacc[r] + bias_v;
            }
        }
    }
}

// =====================================================================
extern "C" void kernel_launch(void* const* d_in, const int* in_sizes, int n_in,
                              void* d_out, int out_size, void* d_ws, size_t ws_size,
                              hipStream_t stream)
{
    const float* x     = (const float*)d_in[0];   // [16384,128]
    const float* Win   = (const float*)d_in[1];   // [384,128]
    const float* bin   = (const float*)d_in[2];   // [384]
    const float* Wout  = (const float*)d_in[3];   // [128,128]
    const float* bout  = (const float*)d_in[4];   // [128]
    const float* alpha = (const float*)d_in[5];   // [16384,8]
    const float* dist2 = (const float*)d_in[6];   // [524288,16]
    // d_in[7] edges, d_in[8] batch: dense block structure, derived analytically

    fused_attn_kernel<<<dim3(512), 512, 0, stream>>>(
        x, Win, bin, Wout, bout, alpha, dist2, (float*)d_out);
}